// Round 4
// baseline (1317.078 us; speedup 1.0000x reference)
//
#include <hip/hip_runtime.h>
#include <stdint.h>

#define NVERT 100000
#define NEDGE 50000
#define DIM 128
#define NNZ_N 1600000

// ---------- dual-dtype load: external "float" inputs may be f32 or bf16 ----------
__device__ __forceinline__ float ldf(const void* p, long i, int bf) {
  if (bf) {
    union { unsigned u; float f; } v;
    v.u = (unsigned)((const unsigned short*)p)[i] << 16;
    return v.f;
  }
  return ((const float*)p)[i];
}

// detect: even-index u16s of f32 data have uniform exponent fields (~16% in
// window); bf16 data ~100%. Writes flag 1 if bf16.
__global__ __launch_bounds__(1024) void detect_bf16(const unsigned short* __restrict__ x,
                                                    int* __restrict__ flag) {
  __shared__ int cnt;
  if (threadIdx.x == 0) cnt = 0;
  __syncthreads();
  unsigned short h = x[threadIdx.x * 2];
  int e = (h >> 7) & 0xFF;
  atomicAdd(&cnt, (e >= 100 && e <= 140) ? 1 : 0);
  __syncthreads();
  if (threadIdx.x == 0) flag[0] = (cnt > 512) ? 1 : 0;
}

__global__ void cvt_bias(const void* btv, const void* bvm, float* btvf, float* bvmf,
                         const int* flagp) {
  int t = threadIdx.x, bf = *flagp;
  if (t < 128) btvf[t] = ldf(btv, t, bf);
  else bvmf[t - 128] = ldf(bvm, t - 128, bf);
}

// W [128][K] row-major -> Wt [K][128]
__global__ void cvt_transpose(const void* __restrict__ W, float* __restrict__ Wt,
                              const int* flagp, int K) {
  int i = blockIdx.x * 256 + threadIdx.x;
  if (i >= K * 128) return;
  int bf = *flagp;
  int k = i >> 7, n = i & 127;
  Wt[i] = ldf(W, (long)n * K + k, bf);
}

// Wc_t[k][n] = (W_te @ W_em)[n][k]; bc[n] = b_te[n] + sum_j W_te[n][j] b_em[j]
__global__ void fuse_wc(const void* __restrict__ Wte, const void* __restrict__ Wem,
                        const void* __restrict__ bte, const void* __restrict__ bem,
                        float* __restrict__ Wct, float* __restrict__ bcf, const int* flagp) {
  int k = blockIdx.x;    // 0..255
  int n = threadIdx.x;   // 0..127
  int bf = *flagp;
  float acc = 0.f;
  for (int j = 0; j < 128; ++j)
    acc += ldf(Wte, n * 128 + j, bf) * ldf(Wem, j * 256 + k, bf);
  Wct[k * 128 + n] = acc;
  if (k == 0) {
    float b = ldf(bte, n, bf);
    for (int j = 0; j < 128; ++j) b += ldf(Wte, n * 128 + j, bf) * ldf(bem, j, bf);
    bcf[n] = b;
  }
}

// ---------- CSR build ----------
__global__ void count_deg(const int* __restrict__ vi, const int* __restrict__ ei,
                          int* __restrict__ cnt_v, int* __restrict__ cnt_e, int nnz) {
  int i = blockIdx.x * blockDim.x + threadIdx.x;
  if (i < nnz) {
    atomicAdd(&cnt_e[ei[i]], 1);
    atomicAdd(&cnt_v[vi[i]], 1);
  }
}

__global__ __launch_bounds__(1024) void scan_block(const int* __restrict__ in,
                                                   int* __restrict__ out,
                                                   int* __restrict__ bsum, int n) {
  __shared__ int sd[1024];
  const int tid = threadIdx.x;
  const int i = blockIdx.x * 1024 + tid;
  int x = (i < n) ? in[i] : 0;
  sd[tid] = x;
  __syncthreads();
  int v = x;
  for (int s = 1; s < 1024; s <<= 1) {
    int t = (tid >= s) ? sd[tid - s] : 0;
    __syncthreads();
    v += t;
    sd[tid] = v;
    __syncthreads();
  }
  if (i < n) out[i] = v - x;
  if (tid == 1023) bsum[blockIdx.x] = v;
}

__global__ __launch_bounds__(1024) void scan_sums(int* __restrict__ bsum, int nb) {
  __shared__ int sd[1024];
  const int tid = threadIdx.x;
  int x = (tid < nb) ? bsum[tid] : 0;
  sd[tid] = x;
  __syncthreads();
  int v = x;
  for (int s = 1; s < 1024; s <<= 1) {
    int t = (tid >= s) ? sd[tid - s] : 0;
    __syncthreads();
    v += t;
    sd[tid] = v;
    __syncthreads();
  }
  if (tid < nb) bsum[tid] = v - x;
}

__global__ void scan_add(int* __restrict__ out, const int* __restrict__ bsum, int n, int total) {
  int i = blockIdx.x * blockDim.x + threadIdx.x;
  if (i < n) out[i] += bsum[i >> 10];
  if (i == 0) out[n] = total;
}

__global__ void build_adj(const int* __restrict__ vi, const int* __restrict__ ei,
                          int* __restrict__ cur_e, int* __restrict__ cur_v,
                          int* __restrict__ adj_e, int* __restrict__ adj_v, int nnz) {
  int i = blockIdx.x * blockDim.x + threadIdx.x;
  if (i < nnz) {
    int v = vi[i], e = ei[i];
    adj_e[atomicAdd(&cur_e[e], 1)] = v;
    adj_v[atomicAdd(&cur_v[v], 1)] = e;
  }
}

// ---------- segment mean (pull, f32): one wave per segment ----------
__global__ __launch_bounds__(256) void seg_mean_f32(
    const int* __restrict__ off, const int* __restrict__ adj,
    const float* __restrict__ table, float* __restrict__ out, int nseg, int nrows) {
  const int gw = (blockIdx.x * 256 + threadIdx.x) >> 6;
  const int l = threadIdx.x & 63;
  if (gw >= nseg) return;
  const int s = off[gw], e = off[gw + 1];
  float a0 = 0.f, a1 = 0.f;
  for (int i = s; i < e; ++i) {
    int r = adj[i];
    if ((unsigned)r >= (unsigned)nrows) r = 0;
    float2 v = *(const float2*)(table + (long)r * DIM + l * 2);
    a0 += v.x; a1 += v.y;
  }
  float inv = (e > s) ? 1.f / (float)(e - s) : 0.f;
  *(float2*)(out + (long)gw * DIM + l * 2) = make_float2(a0 * inv, a1 * inv);
}

// ---------- f32 VALU GEMM: out[M][128] = A[M][K] @ W^T + bias ----------
// A is external (f32-or-bf16 via flag); SPLIT: k<128 from A0(ext), k>=128 from
// A1 (internal f32). Wt is [K][128] f32 (pre-transposed). Block: 32 rows x 128
// cols; thread: 8 rows x 2 cols. In-place-safe: A1 fully staged to LDS before
// any store (per-block rows only).
template<int K, bool SPLIT>
__global__ __launch_bounds__(256) void gemm_f32(
    const void* __restrict__ A0, const float* __restrict__ A1,
    const float* __restrict__ Wt, const float* __restrict__ biasf,
    float* __restrict__ out, int M, const int* flagp) {
  __shared__ float As[32][K];
  const int tid = threadIdx.x;
  const int r0 = blockIdx.x * 32;
  const int bf = *flagp;

  for (int i = tid; i < 32 * K; i += 256) {
    int r = i / K, k = i % K;
    long row = r0 + r;
    float v = 0.f;
    if (row < M) {
      if (SPLIT) v = (k < 128) ? ldf(A0, row * 128 + k, bf) : A1[row * 128 + (k - 128)];
      else       v = ldf(A0, row * (long)K + k, bf);
    }
    As[r][k] = v;
  }
  __syncthreads();

  const int c2 = (tid & 63) * 2;  // col pair
  const int g = tid >> 6;         // row group 0..3 (8 rows each)
  float2 acc[8];
#pragma unroll
  for (int j = 0; j < 8; ++j) acc[j] = make_float2(0.f, 0.f);

  for (int k4 = 0; k4 < K; k4 += 4) {
    float2 w0 = *(const float2*)(Wt + (k4 + 0) * 128 + c2);
    float2 w1 = *(const float2*)(Wt + (k4 + 1) * 128 + c2);
    float2 w2 = *(const float2*)(Wt + (k4 + 2) * 128 + c2);
    float2 w3 = *(const float2*)(Wt + (k4 + 3) * 128 + c2);
#pragma unroll
    for (int j = 0; j < 8; ++j) {
      float4 a = *(const float4*)(&As[g * 8 + j][k4]);
      acc[j].x += a.x * w0.x + a.y * w1.x + a.z * w2.x + a.w * w3.x;
      acc[j].y += a.x * w0.y + a.y * w1.y + a.z * w2.y + a.w * w3.y;
    }
  }

  float2 bv = *(const float2*)(biasf + c2);
#pragma unroll
  for (int j = 0; j < 8; ++j) {
    long row = r0 + g * 8 + j;
    if (row < M)
      *(float2*)(out + row * DIM + c2) = make_float2(acc[j].x + bv.x, acc[j].y + bv.y);
  }
}

// ---------- LayerNorm + ReLU: one wave per row (in-place safe) ----------
__global__ __launch_bounds__(256) void ln_relu(const float* __restrict__ Z,
                                               float* __restrict__ O,
                                               const void* __restrict__ g,
                                               const void* __restrict__ b,
                                               const int* flagp, int M) {
  const int gw = (blockIdx.x * 256 + threadIdx.x) >> 6;
  const int l = threadIdx.x & 63;
  if (gw >= M) return;
  const int bf = *flagp;
  float2 z = *(const float2*)(Z + (long)gw * DIM + l * 2);
  float s = z.x + z.y, q = z.x * z.x + z.y * z.y;
#pragma unroll
  for (int m = 1; m <= 32; m <<= 1) {
    s += __shfl_xor(s, m, 64);
    q += __shfl_xor(q, m, 64);
  }
  float mean = s * (1.f / 128.f);
  float var = q * (1.f / 128.f) - mean * mean;
  float rs = rsqrtf(var + 1e-5f);
  float g0 = ldf(g, l * 2, bf), g1 = ldf(g, l * 2 + 1, bf);
  float b0 = ldf(b, l * 2, bf), b1 = ldf(b, l * 2 + 1, bf);
  float o0 = (z.x - mean) * rs * g0 + b0; o0 = o0 > 0.f ? o0 : 0.f;
  float o1 = (z.y - mean) * rs * g1 + b1; o1 = o1 > 0.f ? o1 : 0.f;
  *(float2*)(O + (long)gw * DIM + l * 2) = make_float2(o0, o1);
}

extern "C" void kernel_launch(void* const* d_in, const int* in_sizes, int n_in,
                              void* d_out, int out_size, void* d_ws, size_t ws_size,
                              hipStream_t stream) {
  const void* X    = d_in[0];
  const void* Y    = d_in[1];
  const int*  v_idx = (const int*)d_in[2];
  const int*  e_idx = (const int*)d_in[3];
  const void* W_tv = d_in[4];
  const void* b_tv = d_in[5];
  const void* W_te = d_in[6];
  const void* b_te = d_in[7];
  const void* W_em = d_in[8];
  const void* b_em = d_in[9];
  const void* W_vm = d_in[10];
  const void* b_vm = d_in[11];
  const void* g_v  = d_in[12];
  const void* be_v = d_in[13];
  const void* g_e  = d_in[14];
  const void* be_e = d_in[15];

  // d_out (f32, 76.8 MB) doubles as staging with exact liveness packing:
  //  [0,51.2M):  Xp -> msg_v -> Xm (in-place) -> Xo (in-place)
  //  [51.2,76.8): msg_e -> Yo
  float* Xp    = (float*)d_out;
  float* msg_e = (float*)d_out + (long)NVERT * DIM;
  float* msg_v = (float*)d_out;            // over dead Xp
  float* Xm    = msg_v;                    // in-place (per-block rows)
  float* Xo    = (float*)d_out;            // in-place (per-wave rows)
  float* Yo    = (float*)d_out + (long)NVERT * DIM;  // over dead msg_e

  // ws ~40 MB
  char* p = (char*)d_ws;
  auto alloc = [&](size_t n) { char* r = p; p += (n + 255) & ~(size_t)255; return r; };
  int*   flag   = (int*)alloc(4);
  float* btv_f  = (float*)alloc(DIM * 4);
  float* bvm_f  = (float*)alloc(DIM * 4);
  float* bc_f   = (float*)alloc(DIM * 4);
  float* Wtv_t  = (float*)alloc(DIM * DIM * 4);        // [128][128]
  float* Wvm_t  = (float*)alloc(2 * DIM * DIM * 4);    // [256][128]
  float* Wc_t   = (float*)alloc(2 * DIM * DIM * 4);    // [256][128]
  float* Ym     = (float*)alloc((long)NEDGE * DIM * 4);  // 25.6 MB
  int* off_e  = (int*)alloc((NEDGE + 1) * 4);
  int* off_v  = (int*)alloc((NVERT + 1) * 4);
  int* cur_e  = (int*)alloc(NEDGE * 4);
  int* cur_v  = (int*)alloc(NVERT * 4);
  int* bsum_e = (int*)alloc(((NEDGE + 1023) / 1024) * 4);
  int* bsum_v = (int*)alloc(((NVERT + 1023) / 1024) * 4);
  int* adj_e  = (int*)alloc((long)NNZ_N * 4);
  int* adj_v  = (int*)alloc((long)NNZ_N * 4);

  // ---- dtype detect + weight prep ----
  detect_bf16<<<1, 1024, 0, stream>>>((const unsigned short*)X, flag);
  cvt_bias<<<1, 256, 0, stream>>>(b_tv, b_vm, btv_f, bvm_f, flag);
  cvt_transpose<<<(DIM * DIM + 255) / 256, 256, 0, stream>>>(W_tv, Wtv_t, flag, 128);
  cvt_transpose<<<(2 * DIM * DIM + 255) / 256, 256, 0, stream>>>(W_vm, Wvm_t, flag, 256);
  fuse_wc<<<256, 128, 0, stream>>>(W_te, W_em, b_te, b_em, Wc_t, bc_f, flag);

  // ---- CSR build ----
  hipMemsetAsync(cur_e, 0, NEDGE * 4, stream);
  hipMemsetAsync(cur_v, 0, NVERT * 4, stream);
  count_deg<<<(NNZ_N + 255) / 256, 256, 0, stream>>>(v_idx, e_idx, cur_v, cur_e, NNZ_N);
  {
    int nbe = (NEDGE + 1023) / 1024, nbv = (NVERT + 1023) / 1024;
    scan_block<<<nbe, 1024, 0, stream>>>(cur_e, off_e, bsum_e, NEDGE);
    scan_block<<<nbv, 1024, 0, stream>>>(cur_v, off_v, bsum_v, NVERT);
    scan_sums<<<1, 1024, 0, stream>>>(bsum_e, nbe);
    scan_sums<<<1, 1024, 0, stream>>>(bsum_v, nbv);
    scan_add<<<(NEDGE + 255) / 256, 256, 0, stream>>>(off_e, bsum_e, NEDGE, NNZ_N);
    scan_add<<<(NVERT + 255) / 256, 256, 0, stream>>>(off_v, bsum_v, NVERT, NNZ_N);
  }
  hipMemcpyAsync(cur_e, off_e, NEDGE * 4, hipMemcpyDeviceToDevice, stream);
  hipMemcpyAsync(cur_v, off_v, NVERT * 4, hipMemcpyDeviceToDevice, stream);
  build_adj<<<(NNZ_N + 255) / 256, 256, 0, stream>>>(v_idx, e_idx, cur_e, cur_v, adj_e, adj_v, NNZ_N);

  // ---- network (all f32) ----
  // Xp = X @ W_tv^T + b_tv
  gemm_f32<128, false><<<(NVERT + 31) / 32, 256, 0, stream>>>(
      X, nullptr, Wtv_t, btv_f, Xp, NVERT, flag);
  // msg_e = seg_mean(Xp[v] by e)
  seg_mean_f32<<<(NEDGE + 3) / 4, 256, 0, stream>>>(off_e, adj_e, Xp, msg_e, NEDGE, NVERT);
  // Ym = concat(Y, msg_e) @ Wc^T + bc
  gemm_f32<256, true><<<(NEDGE + 31) / 32, 256, 0, stream>>>(
      Y, msg_e, Wc_t, bc_f, Ym, NEDGE, flag);
  // Yo = relu(LN(Ym))   (overwrites dead msg_e region)
  ln_relu<<<(NEDGE + 3) / 4, 256, 0, stream>>>(Ym, Yo, g_e, be_e, flag, NEDGE);
  // msg_v = seg_mean(Ym[e] by v)   (overwrites dead Xp region)
  seg_mean_f32<<<(NVERT + 3) / 4, 256, 0, stream>>>(off_v, adj_v, Ym, msg_v, NVERT, NEDGE);
  // Xm = concat(X, msg_v) @ W_vm^T + b_vm   (in-place over msg_v; safe per-block)
  gemm_f32<256, true><<<(NVERT + 31) / 32, 256, 0, stream>>>(
      X, msg_v, Wvm_t, bvm_f, Xm, NVERT, flag);
  // Xo = relu(LN(Xm))   (in-place; safe per-wave)
  ln_relu<<<(NVERT + 3) / 4, 256, 0, stream>>>(Xm, Xo, g_v, be_v, flag, NVERT);
}

// Round 5
// 1111.906 us; speedup vs baseline: 1.1845x; 1.1845x over previous
//
#include <hip/hip_runtime.h>
#include <stdint.h>

#define NVERT 100000
#define NEDGE 50000
#define DIM 128
#define NNZ_N 1600000

__device__ __forceinline__ unsigned short f32_to_bf16(float f) {
  union { float f; unsigned u; } v; v.f = f;
  unsigned r = v.u + 0x7fffu + ((v.u >> 16) & 1u);
  return (unsigned short)(r >> 16);
}
__device__ __forceinline__ float bf16_lo(unsigned u) {
  union { unsigned u; float f; } v; v.u = u << 16; return v.f;
}
__device__ __forceinline__ float bf16_hi(unsigned u) {
  union { unsigned u; float f; } v; v.u = u & 0xffff0000u; return v.f;
}
// dual-dtype load of external "float" inputs (f32 or bf16, runtime flag)
__device__ __forceinline__ float ldf(const void* p, long i, int bf) {
  if (bf) {
    union { unsigned u; float f; } v;
    v.u = (unsigned)((const unsigned short*)p)[i] << 16;
    return v.f;
  }
  return ((const float*)p)[i];
}

// detect input dtype: even-index u16s of f32 data have ~uniform exponent bits
__global__ __launch_bounds__(1024) void detect_bf16(const unsigned short* __restrict__ x,
                                                    int* __restrict__ flag) {
  __shared__ int cnt;
  if (threadIdx.x == 0) cnt = 0;
  __syncthreads();
  unsigned short h = x[threadIdx.x * 2];
  int e = (h >> 7) & 0xFF;
  atomicAdd(&cnt, (e >= 100 && e <= 140) ? 1 : 0);
  __syncthreads();
  if (threadIdx.x == 0) flag[0] = (cnt > 512) ? 1 : 0;
}

__global__ void cvt_bias(const void* btv, const void* bvm, float* btvf, float* bvmf,
                         const int* flagp) {
  int t = threadIdx.x, bf = *flagp;
  if (t < 128) btvf[t] = ldf(btv, t, bf);
  else bvmf[t - 128] = ldf(bvm, t - 128, bf);
}

// W [128][K] row-major -> Wt [K][128]
__global__ void cvt_transpose(const void* __restrict__ W, float* __restrict__ Wt,
                              const int* flagp, int K) {
  int i = blockIdx.x * 256 + threadIdx.x;
  if (i >= K * 128) return;
  int bf = *flagp;
  int k = i >> 7, n = i & 127;
  Wt[i] = ldf(W, (long)n * K + k, bf);
}

// Wc_t[k][n] = (W_te @ W_em)[n][k]; bc[n] = b_te[n] + sum_j W_te[n][j] b_em[j]
__global__ void fuse_wc(const void* __restrict__ Wte, const void* __restrict__ Wem,
                        const void* __restrict__ bte, const void* __restrict__ bem,
                        float* __restrict__ Wct, float* __restrict__ bcf, const int* flagp) {
  int k = blockIdx.x;    // 0..255
  int n = threadIdx.x;   // 0..127
  int bf = *flagp;
  float acc = 0.f;
  for (int j = 0; j < 128; ++j)
    acc += ldf(Wte, n * 128 + j, bf) * ldf(Wem, j * 256 + k, bf);
  Wct[k * 128 + n] = acc;
  if (k == 0) {
    float b = ldf(bte, n, bf);
    for (int j = 0; j < 128; ++j) b += ldf(Wte, n * 128 + j, bf) * ldf(bem, j, bf);
    bcf[n] = b;
  }
}

// ---------- CSR build ----------
__global__ void count_deg4(const int4* __restrict__ vi, const int4* __restrict__ ei,
                           int* __restrict__ cnt_v, int* __restrict__ cnt_e, int n4) {
  int i = blockIdx.x * blockDim.x + threadIdx.x;
  if (i < n4) {
    int4 e = ei[i], v = vi[i];
    atomicAdd(&cnt_e[e.x], 1); atomicAdd(&cnt_e[e.y], 1);
    atomicAdd(&cnt_e[e.z], 1); atomicAdd(&cnt_e[e.w], 1);
    atomicAdd(&cnt_v[v.x], 1); atomicAdd(&cnt_v[v.y], 1);
    atomicAdd(&cnt_v[v.z], 1); atomicAdd(&cnt_v[v.w], 1);
  }
}

__global__ __launch_bounds__(1024) void scan_block(const int* __restrict__ in,
                                                   int* __restrict__ out,
                                                   int* __restrict__ bsum, int n) {
  __shared__ int sd[1024];
  const int tid = threadIdx.x;
  const int i = blockIdx.x * 1024 + tid;
  int x = (i < n) ? in[i] : 0;
  sd[tid] = x;
  __syncthreads();
  int v = x;
  for (int s = 1; s < 1024; s <<= 1) {
    int t = (tid >= s) ? sd[tid - s] : 0;
    __syncthreads();
    v += t;
    sd[tid] = v;
    __syncthreads();
  }
  if (i < n) out[i] = v - x;
  if (tid == 1023) bsum[blockIdx.x] = v;
}

__global__ __launch_bounds__(1024) void scan_sums(int* __restrict__ bsum, int nb) {
  __shared__ int sd[1024];
  const int tid = threadIdx.x;
  int x = (tid < nb) ? bsum[tid] : 0;
  sd[tid] = x;
  __syncthreads();
  int v = x;
  for (int s = 1; s < 1024; s <<= 1) {
    int t = (tid >= s) ? sd[tid - s] : 0;
    __syncthreads();
    v += t;
    sd[tid] = v;
    __syncthreads();
  }
  if (tid < nb) bsum[tid] = v - x;
}

__global__ void scan_add(int* __restrict__ out, const int* __restrict__ bsum, int n, int total) {
  int i = blockIdx.x * blockDim.x + threadIdx.x;
  if (i < n) out[i] += bsum[i >> 10];
  if (i == 0) out[n] = total;
}

// nontemporal scatter: A/B test vs R4's 16x write amplification (198 MB)
__global__ void build_adj(const int* __restrict__ vi, const int* __restrict__ ei,
                          int* __restrict__ cur_e, int* __restrict__ cur_v,
                          int* __restrict__ adj_e, int* __restrict__ adj_v, int nnz) {
  int i = blockIdx.x * blockDim.x + threadIdx.x;
  if (i < nnz) {
    int v = vi[i], e = ei[i];
    int pe = atomicAdd(&cur_e[e], 1);
    __builtin_nontemporal_store(v, &adj_e[pe]);
    int pv = atomicAdd(&cur_v[v], 1);
    __builtin_nontemporal_store(e, &adj_v[pv]);
  }
}

// ---------- segment mean: 4 segments/wave, 16 lanes x 8 cols, bf16 table ----------
__global__ __launch_bounds__(256) void seg_mean_q(
    const int* __restrict__ off, const int* __restrict__ adj,
    const unsigned short* __restrict__ tbl, float* __restrict__ out,
    int nseg, int nrows) {
  const int seg = (blockIdx.x * 256 + threadIdx.x) >> 4;
  const int l = threadIdx.x & 15;
  if (seg >= nseg) return;
  const int s = off[seg], e = off[seg + 1];
  float a0 = 0, a1 = 0, a2 = 0, a3 = 0, a4 = 0, a5 = 0, a6 = 0, a7 = 0;
  for (int i = s; i < e; ++i) {
    int r = adj[i];
    if ((unsigned)r >= (unsigned)nrows) r = 0;
    uint4 u = *(const uint4*)(tbl + (long)r * DIM + l * 8);
    a0 += bf16_lo(u.x); a1 += bf16_hi(u.x);
    a2 += bf16_lo(u.y); a3 += bf16_hi(u.y);
    a4 += bf16_lo(u.z); a5 += bf16_hi(u.z);
    a6 += bf16_lo(u.w); a7 += bf16_hi(u.w);
  }
  float inv = (e > s) ? 1.f / (float)(e - s) : 0.f;
  float* op = out + (long)seg * DIM + l * 8;
  *(float4*)op       = make_float4(a0 * inv, a1 * inv, a2 * inv, a3 * inv);
  *(float4*)(op + 4) = make_float4(a4 * inv, a5 * inv, a6 * inv, a7 * inv);
}

// ---------- f32 VALU GEMM + fused epilogues ----------
// out[M][128] = A[M][K] @ Wt + bias. Block: 32 rows x 128 cols; thread: 8r x 2c.
// Row group g = wave g -> LN reduction is an in-wave shfl. In-place safe:
// block stages all its A rows to LDS before any store.
template<int K, bool SPLIT, bool DO_LN, bool STORE_BF16>
__global__ __launch_bounds__(256) void gemm_f32(
    const void* __restrict__ A0, const float* __restrict__ A1,
    const float* __restrict__ Wt, const float* __restrict__ biasf,
    unsigned short* __restrict__ outb, float* __restrict__ outf,
    const void* __restrict__ gw_, const void* __restrict__ bw_,
    int M, const int* flagp) {
  __shared__ float As[32][K];
  const int tid = threadIdx.x;
  const int r0 = blockIdx.x * 32;
  const int bf = *flagp;

  for (int i = tid; i < 32 * K; i += 256) {
    int r = i / K, k = i % K;
    long row = r0 + r;
    float v = 0.f;
    if (row < M) {
      if (SPLIT) v = (k < 128) ? ldf(A0, row * 128 + k, bf) : A1[row * 128 + (k - 128)];
      else       v = ldf(A0, row * (long)K + k, bf);
    }
    As[r][k] = v;
  }
  __syncthreads();

  const int c2 = (tid & 63) * 2;
  const int g = tid >> 6;
  float2 acc[8];
#pragma unroll
  for (int j = 0; j < 8; ++j) acc[j] = make_float2(0.f, 0.f);

  for (int k4 = 0; k4 < K; k4 += 4) {
    float2 w0 = *(const float2*)(Wt + (k4 + 0) * 128 + c2);
    float2 w1 = *(const float2*)(Wt + (k4 + 1) * 128 + c2);
    float2 w2 = *(const float2*)(Wt + (k4 + 2) * 128 + c2);
    float2 w3 = *(const float2*)(Wt + (k4 + 3) * 128 + c2);
#pragma unroll
    for (int j = 0; j < 8; ++j) {
      float4 a = *(const float4*)(&As[g * 8 + j][k4]);
      acc[j].x += a.x * w0.x + a.y * w1.x + a.z * w2.x + a.w * w3.x;
      acc[j].y += a.x * w0.y + a.y * w1.y + a.z * w2.y + a.w * w3.y;
    }
  }

  float2 bv = *(const float2*)(biasf + c2);
#pragma unroll
  for (int j = 0; j < 8; ++j) { acc[j].x += bv.x; acc[j].y += bv.y; }

  if (STORE_BF16) {
#pragma unroll
    for (int j = 0; j < 8; ++j) {
      long row = r0 + g * 8 + j;
      if (row < M) {
        ushort2 h = make_ushort2(f32_to_bf16(acc[j].x), f32_to_bf16(acc[j].y));
        *(ushort2*)(outb + row * DIM + c2) = h;
      }
    }
  }

  if (DO_LN) {
    float gv0 = ldf(gw_, c2, bf), gv1 = ldf(gw_, c2 + 1, bf);
    float bv0 = ldf(bw_, c2, bf), bv1 = ldf(bw_, c2 + 1, bf);
#pragma unroll
    for (int j = 0; j < 8; ++j) {
      float s = acc[j].x + acc[j].y;
      float q = acc[j].x * acc[j].x + acc[j].y * acc[j].y;
#pragma unroll
      for (int m = 1; m <= 32; m <<= 1) {
        s += __shfl_xor(s, m, 64);
        q += __shfl_xor(q, m, 64);
      }
      float mean = s * (1.f / 128.f);
      float var = q * (1.f / 128.f) - mean * mean;
      float rs = rsqrtf(var + 1e-5f);
      float o0 = (acc[j].x - mean) * rs * gv0 + bv0; o0 = o0 > 0.f ? o0 : 0.f;
      float o1 = (acc[j].y - mean) * rs * gv1 + bv1; o1 = o1 > 0.f ? o1 : 0.f;
      long row = r0 + g * 8 + j;
      if (row < M) *(float2*)(outf + row * DIM + c2) = make_float2(o0, o1);
    }
  }
}

extern "C" void kernel_launch(void* const* d_in, const int* in_sizes, int n_in,
                              void* d_out, int out_size, void* d_ws, size_t ws_size,
                              hipStream_t stream) {
  const void* X    = d_in[0];
  const void* Y    = d_in[1];
  const int*  v_idx = (const int*)d_in[2];
  const int*  e_idx = (const int*)d_in[3];
  const void* W_tv = d_in[4];
  const void* b_tv = d_in[5];
  const void* W_te = d_in[6];
  const void* b_te = d_in[7];
  const void* W_em = d_in[8];
  const void* b_em = d_in[9];
  const void* W_vm = d_in[10];
  const void* b_vm = d_in[11];
  const void* g_v  = d_in[12];
  const void* be_v = d_in[13];
  const void* g_e  = d_in[14];
  const void* be_e = d_in[15];

  // d_out (76.8 MB f32) liveness packing:
  //  [0,25.6M):  Xp(bf16) -> dead -> (msg_v/Xo below span it)
  //  [0,51.2M):  msg_v(f32) -> Xo(f32) in-place
  //  [51.2,76.8M): msg_e(f32) -> Yo(f32) in-place
  unsigned short* Xp_b = (unsigned short*)d_out;
  float* msg_e = (float*)d_out + (long)NVERT * DIM;
  float* Yo    = msg_e;
  float* msg_v = (float*)d_out;
  float* Xo    = (float*)d_out;

  // ws ~26 MB
  char* p = (char*)d_ws;
  auto alloc = [&](size_t n) { char* r = p; p += (n + 255) & ~(size_t)255; return r; };
  int*   flag  = (int*)alloc(4);
  float* btv_f = (float*)alloc(DIM * 4);
  float* bvm_f = (float*)alloc(DIM * 4);
  float* bc_f  = (float*)alloc(DIM * 4);
  float* Wtv_t = (float*)alloc(DIM * DIM * 4);
  float* Wvm_t = (float*)alloc(2 * DIM * DIM * 4);
  float* Wc_t  = (float*)alloc(2 * DIM * DIM * 4);
  unsigned short* Ym_b = (unsigned short*)alloc((long)NEDGE * DIM * 2);  // 12.8 MB
  int* off_e  = (int*)alloc((NEDGE + 1) * 4);
  int* off_v  = (int*)alloc((NVERT + 1) * 4);
  int* cur_e  = (int*)alloc(NEDGE * 4);
  int* cur_v  = (int*)alloc(NVERT * 4);
  int* bsum_e = (int*)alloc(((NEDGE + 1023) / 1024) * 4);
  int* bsum_v = (int*)alloc(((NVERT + 1023) / 1024) * 4);
  int* adj_e  = (int*)alloc((long)NNZ_N * 4);
  int* adj_v  = (int*)alloc((long)NNZ_N * 4);

  // ---- dtype detect + weight prep ----
  detect_bf16<<<1, 1024, 0, stream>>>((const unsigned short*)X, flag);
  cvt_bias<<<1, 256, 0, stream>>>(b_tv, b_vm, btv_f, bvm_f, flag);
  cvt_transpose<<<(DIM * DIM + 255) / 256, 256, 0, stream>>>(W_tv, Wtv_t, flag, 128);
  cvt_transpose<<<(2 * DIM * DIM + 255) / 256, 256, 0, stream>>>(W_vm, Wvm_t, flag, 256);
  fuse_wc<<<256, 128, 0, stream>>>(W_te, W_em, b_te, b_em, Wc_t, bc_f, flag);

  // ---- CSR build ----
  hipMemsetAsync(cur_e, 0, NEDGE * 4, stream);
  hipMemsetAsync(cur_v, 0, NVERT * 4, stream);
  count_deg4<<<(NNZ_N / 4 + 255) / 256, 256, 0, stream>>>(
      (const int4*)v_idx, (const int4*)e_idx, cur_v, cur_e, NNZ_N / 4);
  {
    int nbe = (NEDGE + 1023) / 1024, nbv = (NVERT + 1023) / 1024;
    scan_block<<<nbe, 1024, 0, stream>>>(cur_e, off_e, bsum_e, NEDGE);
    scan_block<<<nbv, 1024, 0, stream>>>(cur_v, off_v, bsum_v, NVERT);
    scan_sums<<<1, 1024, 0, stream>>>(bsum_e, nbe);
    scan_sums<<<1, 1024, 0, stream>>>(bsum_v, nbv);
    scan_add<<<(NEDGE + 255) / 256, 256, 0, stream>>>(off_e, bsum_e, NEDGE, NNZ_N);
    scan_add<<<(NVERT + 255) / 256, 256, 0, stream>>>(off_v, bsum_v, NVERT, NNZ_N);
  }
  hipMemcpyAsync(cur_e, off_e, NEDGE * 4, hipMemcpyDeviceToDevice, stream);
  hipMemcpyAsync(cur_v, off_v, NVERT * 4, hipMemcpyDeviceToDevice, stream);
  build_adj<<<(NNZ_N + 255) / 256, 256, 0, stream>>>(v_idx, e_idx, cur_e, cur_v, adj_e, adj_v, NNZ_N);

  // ---- network ----
  // Xp(bf16) = X @ W_tv^T + b_tv
  gemm_f32<128, false, false, true><<<(NVERT + 31) / 32, 256, 0, stream>>>(
      X, nullptr, Wtv_t, btv_f, Xp_b, nullptr, nullptr, nullptr, NVERT, flag);
  // msg_e(f32) = seg_mean(Xp[v] by e)
  seg_mean_q<<<(NEDGE + 15) / 16, 256, 0, stream>>>(off_e, adj_e, Xp_b, msg_e, NEDGE, NVERT);
  // Ym(bf16) = concat(Y, msg_e) @ Wc^T + bc ; Yo = relu(LN(Ym)) [in-place over msg_e]
  gemm_f32<256, true, true, true><<<(NEDGE + 31) / 32, 256, 0, stream>>>(
      Y, msg_e, Wc_t, bc_f, Ym_b, Yo, g_e, be_e, NEDGE, flag);
  // msg_v(f32) = seg_mean(Ym[e] by v) [overwrites dead Xp]
  seg_mean_q<<<(NVERT + 15) / 16, 256, 0, stream>>>(off_v, adj_v, Ym_b, msg_v, NVERT, NEDGE);
  // Xo = relu(LN(concat(X, msg_v) @ W_vm^T + b_vm)) [in-place over msg_v]
  gemm_f32<256, true, true, false><<<(NVERT + 31) / 32, 256, 0, stream>>>(
      X, msg_v, Wvm_t, bvm_f, nullptr, Xo, g_v, be_v, NVERT, flag);
}

// Round 6
// 1029.765 us; speedup vs baseline: 1.2790x; 1.0798x over previous
//
#include <hip/hip_runtime.h>
#include <stdint.h>

#define NVERT 100000
#define NEDGE 50000
#define DIM 128
#define NNZ_N 1600000
#define NB_E 1563            // ceil(50000/32) buckets of 32 edges
#define NB_V 1563            // ceil(100000/64) buckets of 64 verts
#define NSUB 25008           // (NB_E + NB_V) * 8 residue sub-buckets
#define NBKT 3126            // NB_E + NB_V

typedef __attribute__((ext_vector_type(8))) short bf16x8;
typedef __attribute__((ext_vector_type(4))) float f32x4;

__device__ __forceinline__ unsigned short f32_to_bf16(float f) {
  union { float f; unsigned u; } v; v.f = f;
  unsigned r = v.u + 0x7fffu + ((v.u >> 16) & 1u);
  return (unsigned short)(r >> 16);
}
__device__ __forceinline__ float bf16_lo(unsigned u) {
  union { unsigned u; float f; } v; v.u = u << 16; return v.f;
}
__device__ __forceinline__ float bf16_hi(unsigned u) {
  union { unsigned u; float f; } v; v.u = u & 0xffff0000u; return v.f;
}
// dual-dtype load of external "float" inputs (f32 or bf16, runtime flag)
__device__ __forceinline__ float ldf(const void* p, long i, int bf) {
  if (bf) {
    union { unsigned u; float f; } v;
    v.u = (unsigned)((const unsigned short*)p)[i] << 16;
    return v.f;
  }
  return ((const float*)p)[i];
}
// 8-elem bf16 MFMA fragment from external (flag) array at element idx
__device__ __forceinline__ bf16x8 frag_ext(const void* A, long idx, int bf) {
  if (bf) return *(const bf16x8*)((const unsigned short*)A + idx);
  const float* f = (const float*)A + idx;
  float4 f0 = *(const float4*)f, f1 = *(const float4*)(f + 4);
  bf16x8 r;
  r[0] = (short)f32_to_bf16(f0.x); r[1] = (short)f32_to_bf16(f0.y);
  r[2] = (short)f32_to_bf16(f0.z); r[3] = (short)f32_to_bf16(f0.w);
  r[4] = (short)f32_to_bf16(f1.x); r[5] = (short)f32_to_bf16(f1.y);
  r[6] = (short)f32_to_bf16(f1.z); r[7] = (short)f32_to_bf16(f1.w);
  return r;
}
__device__ __forceinline__ bf16x8 frag_f32(const float* f) {
  float4 f0 = *(const float4*)f, f1 = *(const float4*)(f + 4);
  bf16x8 r;
  r[0] = (short)f32_to_bf16(f0.x); r[1] = (short)f32_to_bf16(f0.y);
  r[2] = (short)f32_to_bf16(f0.z); r[3] = (short)f32_to_bf16(f0.w);
  r[4] = (short)f32_to_bf16(f1.x); r[5] = (short)f32_to_bf16(f1.y);
  r[6] = (short)f32_to_bf16(f1.z); r[7] = (short)f32_to_bf16(f1.w);
  return r;
}

// detect input dtype: even-index u16s of f32 data have ~uniform exponent bits
__global__ __launch_bounds__(1024) void detect_bf16(const unsigned short* __restrict__ x,
                                                    int* __restrict__ flag) {
  __shared__ int cnt;
  if (threadIdx.x == 0) cnt = 0;
  __syncthreads();
  unsigned short h = x[threadIdx.x * 2];
  int e = (h >> 7) & 0xFF;
  atomicAdd(&cnt, (e >= 100 && e <= 140) ? 1 : 0);
  __syncthreads();
  if (threadIdx.x == 0) flag[0] = (cnt > 512) ? 1 : 0;
}

__global__ void cvt_bias(const void* btv, const void* bvm, float* btvf, float* bvmf,
                         const int* flagp) {
  int t = threadIdx.x, bf = *flagp;
  if (t < 128) btvf[t] = ldf(btv, t, bf);
  else bvmf[t - 128] = ldf(bvm, t - 128, bf);
}

// weights -> bf16, layout unchanged ([n][k] row-major = MFMA B-fragment layout)
__global__ void cvt_wb16(const void* __restrict__ W, unsigned short* __restrict__ Wb,
                         const int* flagp, int n) {
  int i = blockIdx.x * 256 + threadIdx.x;
  if (i < n) Wb[i] = f32_to_bf16(ldf(W, i, *flagp));
}

// Wc[n][k] = (W_te @ W_em)[n][k] bf16; bc[n] = b_te[n] + sum_j W_te[n][j] b_em[j]
__global__ void fuse_wc(const void* __restrict__ Wte, const void* __restrict__ Wem,
                        const void* __restrict__ bte, const void* __restrict__ bem,
                        unsigned short* __restrict__ Wc, float* __restrict__ bcf,
                        const int* flagp) {
  int n = blockIdx.x;    // 0..127
  int k = threadIdx.x;   // 0..255
  int bf = *flagp;
  float acc = 0.f;
  for (int j = 0; j < 128; ++j)
    acc += ldf(Wte, n * 128 + j, bf) * ldf(Wem, j * 256 + k, bf);
  Wc[n * 256 + k] = f32_to_bf16(acc);
  if (k == 0) {
    float b = ldf(bte, n, bf);
    for (int j = 0; j < 128; ++j) b += ldf(Wte, n * 128 + j, bf) * ldf(bem, j, bf);
    bcf[n] = b;
  }
}

// ---------- CSR build: histogram (per-segment + per-sub-bucket) ----------
// res = blockIdx&7 must match part_pairs (same grid shape & indexing).
__global__ void count_all(const int4* __restrict__ vi, const int4* __restrict__ ei,
                          int* __restrict__ cnt_v, int* __restrict__ cnt_e,
                          int* __restrict__ scnt, int n4) {
  int i = blockIdx.x * blockDim.x + threadIdx.x;
  if (i >= n4) return;
  int res = blockIdx.x & 7;
  int4 e = ei[i], v = vi[i];
  atomicAdd(&cnt_e[e.x], 1); atomicAdd(&scnt[((e.x >> 5) << 3) | res], 1);
  atomicAdd(&cnt_e[e.y], 1); atomicAdd(&scnt[((e.y >> 5) << 3) | res], 1);
  atomicAdd(&cnt_e[e.z], 1); atomicAdd(&scnt[((e.z >> 5) << 3) | res], 1);
  atomicAdd(&cnt_e[e.w], 1); atomicAdd(&scnt[((e.w >> 5) << 3) | res], 1);
  atomicAdd(&cnt_v[v.x], 1); atomicAdd(&scnt[(NB_E * 8) + (((v.x >> 6) << 3) | res)], 1);
  atomicAdd(&cnt_v[v.y], 1); atomicAdd(&scnt[(NB_E * 8) + (((v.y >> 6) << 3) | res)], 1);
  atomicAdd(&cnt_v[v.z], 1); atomicAdd(&scnt[(NB_E * 8) + (((v.z >> 6) << 3) | res)], 1);
  atomicAdd(&cnt_v[v.w], 1); atomicAdd(&scnt[(NB_E * 8) + (((v.w >> 6) << 3) | res)], 1);
}

__global__ __launch_bounds__(1024) void scan_block(const int* __restrict__ in,
                                                   int* __restrict__ out,
                                                   int* __restrict__ bsum, int n) {
  __shared__ int sd[1024];
  const int tid = threadIdx.x;
  const int i = blockIdx.x * 1024 + tid;
  int x = (i < n) ? in[i] : 0;
  sd[tid] = x;
  __syncthreads();
  int v = x;
  for (int s = 1; s < 1024; s <<= 1) {
    int t = (tid >= s) ? sd[tid - s] : 0;
    __syncthreads();
    v += t;
    sd[tid] = v;
    __syncthreads();
  }
  if (i < n) out[i] = v - x;
  if (tid == 1023) bsum[blockIdx.x] = v;
}

__global__ __launch_bounds__(1024) void scan_sums(int* __restrict__ bsum, int nb) {
  __shared__ int sd[1024];
  const int tid = threadIdx.x;
  int x = (tid < nb) ? bsum[tid] : 0;
  sd[tid] = x;
  __syncthreads();
  int v = x;
  for (int s = 1; s < 1024; s <<= 1) {
    int t = (tid >= s) ? sd[tid - s] : 0;
    __syncthreads();
    v += t;
    sd[tid] = v;
    __syncthreads();
  }
  if (tid < nb) bsum[tid] = v - x;
}

__global__ void scan_add(int* __restrict__ out, const int* __restrict__ bsum, int n, int total) {
  int i = blockIdx.x * blockDim.x + threadIdx.x;
  if (i < n) out[i] += bsum[i >> 10];
  if (i == 0) out[n] = total;
}

// ---------- phase 1: partition pairs into sub-buckets (dense append streams) ----------
__global__ void part_pairs(const int4* __restrict__ vi, const int4* __restrict__ ei,
                           int* __restrict__ scur, uint2* __restrict__ pair, int n4) {
  int i = blockIdx.x * blockDim.x + threadIdx.x;
  if (i >= n4) return;
  int res = blockIdx.x & 7;
  int4 e = ei[i], v = vi[i];
#define PP(ee, vv)                                                            \
  {                                                                           \
    int p1 = atomicAdd(&scur[(((ee) >> 5) << 3) | res], 1);                   \
    pair[p1] = make_uint2((unsigned)(ee), (unsigned)(vv));                    \
    int p2 = atomicAdd(&scur[(NB_E * 8) + ((((vv) >> 6) << 3) | res)], 1);    \
    pair[p2] = make_uint2((unsigned)(vv), (unsigned)(ee));                    \
  }
  PP(e.x, v.x) PP(e.y, v.y) PP(e.z, v.z) PP(e.w, v.w)
#undef PP
}

// ---------- phase 2: one block per bucket -> scatter into ~4KB adj window ----------
__global__ __launch_bounds__(256) void scatter_adj(const uint2* __restrict__ pair,
                                                   const int* __restrict__ sbase,
                                                   int* __restrict__ cur_e,
                                                   int* __restrict__ cur_v,
                                                   int* __restrict__ adj_e,
                                                   int* __restrict__ adj_v) {
  int b = blockIdx.x;  // 0..NBKT-1 (e-buckets then v-buckets, contiguous)
  int s0 = sbase[b * 8], s1 = sbase[b * 8 + 8];
  int* cur = (b < NB_E) ? cur_e : cur_v;
  int* adj = (b < NB_E) ? adj_e : adj_v;
  for (int i = s0 + threadIdx.x; i < s1; i += 256) {
    uint2 p = pair[i];
    int pos = atomicAdd(&cur[p.x], 1);
    adj[pos] = p.y;
  }
}

// ---------- segment mean: 4 segs/wave, 16 lanes x 8 cols, x4-unrolled gather ----------
__global__ __launch_bounds__(256) void seg_mean_q(
    const int* __restrict__ off, const int* __restrict__ adj,
    const unsigned short* __restrict__ tbl, float* __restrict__ out,
    int nseg, int nrows) {
  const int seg = (blockIdx.x * 256 + threadIdx.x) >> 4;
  const int l = threadIdx.x & 15;
  if (seg >= nseg) return;
  const int s = off[seg], e = off[seg + 1];
  float a0 = 0, a1 = 0, a2 = 0, a3 = 0, a4 = 0, a5 = 0, a6 = 0, a7 = 0;
#define ACC(u)                                         \
  a0 += bf16_lo(u.x); a1 += bf16_hi(u.x);              \
  a2 += bf16_lo(u.y); a3 += bf16_hi(u.y);              \
  a4 += bf16_lo(u.z); a5 += bf16_hi(u.z);              \
  a6 += bf16_lo(u.w); a7 += bf16_hi(u.w);
  int i = s;
  for (; i + 4 <= e; i += 4) {
    int r0 = adj[i], r1 = adj[i + 1], r2 = adj[i + 2], r3 = adj[i + 3];
    if ((unsigned)r0 >= (unsigned)nrows) r0 = 0;
    if ((unsigned)r1 >= (unsigned)nrows) r1 = 0;
    if ((unsigned)r2 >= (unsigned)nrows) r2 = 0;
    if ((unsigned)r3 >= (unsigned)nrows) r3 = 0;
    uint4 u0 = *(const uint4*)(tbl + (long)r0 * DIM + l * 8);
    uint4 u1 = *(const uint4*)(tbl + (long)r1 * DIM + l * 8);
    uint4 u2 = *(const uint4*)(tbl + (long)r2 * DIM + l * 8);
    uint4 u3 = *(const uint4*)(tbl + (long)r3 * DIM + l * 8);
    ACC(u0) ACC(u1) ACC(u2) ACC(u3)
  }
  for (; i < e; ++i) {
    int r = adj[i];
    if ((unsigned)r >= (unsigned)nrows) r = 0;
    uint4 u = *(const uint4*)(tbl + (long)r * DIM + l * 8);
    ACC(u)
  }
#undef ACC
  float inv = (e > s) ? 1.f / (float)(e - s) : 0.f;
  float* op = out + (long)seg * DIM + l * 8;
  *(float4*)op       = make_float4(a0 * inv, a1 * inv, a2 * inv, a3 * inv);
  *(float4*)(op + 4) = make_float4(a4 * inv, a5 * inv, a6 * inv, a7 * inv);
}

// ---------- MFMA GEMM: out[M][128] = A[M][K] @ B[128][K]^T + bias (+epilogues) ----------
// wave = 16-row strip x full 128 cols (8 tiles 16x16x32 bf16), no LDS/barriers.
// SPLIT: K=256, k<128 from A0 (external, flag dtype), k>=128 from A1 (internal f32).
// In-place safe (outf may alias A1): rows partitioned per wave; epilogue stores
// data-depend on all A loads of that wave.
template<int KSTEPS, bool SPLIT, bool DO_LN, bool STORE_BF16>
__global__ __launch_bounds__(256) void gemm_mfma(
    const void* __restrict__ A0, const float* __restrict__ A1,
    const unsigned short* __restrict__ Bw, const float* __restrict__ biasf,
    unsigned short* __restrict__ outb, float* __restrict__ outf,
    const void* __restrict__ gw_, const void* __restrict__ bw_,
    int M, const int* flagp) {
  constexpr int K = KSTEPS * 32;
  constexpr int KA0 = SPLIT ? 128 : K;
  const int bf = *flagp;
  const int wave = threadIdx.x >> 6;
  const int lane = threadIdx.x & 63;
  const int m0 = blockIdx.x * 64 + wave * 16;
  if (m0 >= M) return;              // M % 16 == 0 -> wave-level cull is exact
  const int c = lane & 15;          // A row in strip / out col in tile
  const int q = lane >> 4;          // k-chunk selector; C/D row group
  const long arow = m0 + c;

  f32x4 acc[8];
#pragma unroll
  for (int t = 0; t < 8; ++t) acc[t] = (f32x4){0.f, 0.f, 0.f, 0.f};

#pragma unroll
  for (int ks = 0; ks < KSTEPS; ++ks) {
    const int kk = ks * 32 + q * 8;
    bf16x8 a;
    if (SPLIT && ks >= KSTEPS / 2) a = frag_f32(A1 + arow * 128 + (kk - 128));
    else                           a = frag_ext(A0, arow * (long)KA0 + kk, bf);
#pragma unroll
    for (int t = 0; t < 8; ++t) {
      bf16x8 b = *(const bf16x8*)(Bw + (long)(t * 16 + c) * K + kk);
      acc[t] = __builtin_amdgcn_mfma_f32_16x16x32_bf16(a, b, acc[t], 0, 0, 0);
    }
  }

  // C/D layout [m89-verified]: col = t*16 + c, row = m0 + q*4 + reg
#pragma unroll
  for (int t = 0; t < 8; ++t) {
    float bv = biasf[t * 16 + c];
#pragma unroll
    for (int i = 0; i < 4; ++i) acc[t][i] += bv;
  }

  if (STORE_BF16) {
#pragma unroll
    for (int t = 0; t < 8; ++t) {
      int col = t * 16 + c;
#pragma unroll
      for (int i = 0; i < 4; ++i)
        outb[(long)(m0 + q * 4 + i) * DIM + col] = f32_to_bf16(acc[t][i]);
    }
  }

  if (DO_LN) {
    float sum[4] = {0, 0, 0, 0}, sq[4] = {0, 0, 0, 0};
#pragma unroll
    for (int t = 0; t < 8; ++t)
#pragma unroll
      for (int i = 0; i < 4; ++i) { float v = acc[t][i]; sum[i] += v; sq[i] += v * v; }
    // row r = m0+q*4+i spans the 16 lanes sharing q -> xor over lane bits 0..3
#pragma unroll
    for (int m = 1; m <= 8; m <<= 1) {
#pragma unroll
      for (int i = 0; i < 4; ++i) {
        sum[i] += __shfl_xor(sum[i], m, 64);
        sq[i]  += __shfl_xor(sq[i], m, 64);
      }
    }
    float mean[4], rstd[4];
#pragma unroll
    for (int i = 0; i < 4; ++i) {
      mean[i] = sum[i] * (1.0f / 128.0f);
      float var = sq[i] * (1.0f / 128.0f) - mean[i] * mean[i];
      rstd[i] = rsqrtf(var + 1e-5f);
    }
#pragma unroll
    for (int t = 0; t < 8; ++t) {
      int col = t * 16 + c;
      float gv = ldf(gw_, col, bf), bv = ldf(bw_, col, bf);
#pragma unroll
      for (int i = 0; i < 4; ++i) {
        float v = (acc[t][i] - mean[i]) * rstd[i] * gv + bv;
        v = v > 0.f ? v : 0.f;
        outf[(long)(m0 + q * 4 + i) * DIM + col] = v;
      }
    }
  }
}

extern "C" void kernel_launch(void* const* d_in, const int* in_sizes, int n_in,
                              void* d_out, int out_size, void* d_ws, size_t ws_size,
                              hipStream_t stream) {
  const void* X    = d_in[0];
  const void* Y    = d_in[1];
  const int*  v_idx = (const int*)d_in[2];
  const int*  e_idx = (const int*)d_in[3];
  const void* W_tv = d_in[4];
  const void* b_tv = d_in[5];
  const void* W_te = d_in[6];
  const void* b_te = d_in[7];
  const void* W_em = d_in[8];
  const void* b_em = d_in[9];
  const void* W_vm = d_in[10];
  const void* b_vm = d_in[11];
  const void* g_v  = d_in[12];
  const void* be_v = d_in[13];
  const void* g_e  = d_in[14];
  const void* be_e = d_in[15];

  // d_out (76.8 MB) liveness packing:
  //  build:   pair[3.2M x 8B] at bytes [25.6M, 51.2M)
  //  gemm1:   Xp_b(bf16) [0, 25.6M)
  //  seg1:    msg_e(f32) [51.2M, 76.8M)
  //  gemm2:   Yo(f32) in-place over msg_e (same-row aliasing only)
  //  seg2:    msg_v(f32) [0, 51.2M) over dead Xp+pair
  //  gemm3:   Xo(f32) in-place over msg_v (same-row aliasing only)
  unsigned short* Xp_b = (unsigned short*)d_out;
  uint2* pair  = (uint2*)((unsigned short*)d_out + (long)NVERT * DIM);
  float* msg_e = (float*)d_out + (long)NVERT * DIM;
  float* Yo    = msg_e;
  float* msg_v = (float*)d_out;
  float* Xo    = (float*)d_out;

  // ws ~27 MB
  char* p = (char*)d_ws;
  auto alloc = [&](size_t n) { char* r = p; p += (n + 255) & ~(size_t)255; return r; };
  int*   flag  = (int*)alloc(4);
  float* btv_f = (float*)alloc(DIM * 4);
  float* bvm_f = (float*)alloc(DIM * 4);
  float* bc_f  = (float*)alloc(DIM * 4);
  unsigned short* Wtv_b = (unsigned short*)alloc(DIM * DIM * 2);
  unsigned short* Wvm_b = (unsigned short*)alloc(2 * DIM * DIM * 2);
  unsigned short* Wc_b  = (unsigned short*)alloc(2 * DIM * DIM * 2);
  unsigned short* Ym_b  = (unsigned short*)alloc((long)NEDGE * DIM * 2);  // 12.8 MB
  int* off_e  = (int*)alloc((NEDGE + 1) * 4);
  int* off_v  = (int*)alloc((NVERT + 1) * 4);
  int* cur_e  = (int*)alloc(NEDGE * 4);
  int* cur_v  = (int*)alloc(NVERT * 4);
  int* scnt   = (int*)alloc(NSUB * 4);
  int* sbase  = (int*)alloc((NSUB + 1) * 4);
  int* scur   = (int*)alloc(NSUB * 4);
  int* bsum_e = (int*)alloc(((NEDGE + 1023) / 1024) * 4);
  int* bsum_v = (int*)alloc(((NVERT + 1023) / 1024) * 4);
  int* bsum_s = (int*)alloc(((NSUB + 1023) / 1024) * 4);
  int* adj_e  = (int*)alloc((long)NNZ_N * 4);   // 6.4 MB
  int* adj_v  = (int*)alloc((long)NNZ_N * 4);   // 6.4 MB

  // ---- dtype detect + weight prep ----
  detect_bf16<<<1, 1024, 0, stream>>>((const unsigned short*)X, flag);
  cvt_bias<<<1, 256, 0, stream>>>(b_tv, b_vm, btv_f, bvm_f, flag);
  cvt_wb16<<<(DIM * DIM + 255) / 256, 256, 0, stream>>>(W_tv, Wtv_b, flag, DIM * DIM);
  cvt_wb16<<<(2 * DIM * DIM + 255) / 256, 256, 0, stream>>>(W_vm, Wvm_b, flag, 2 * DIM * DIM);
  fuse_wc<<<DIM, 2 * DIM, 0, stream>>>(W_te, W_em, b_te, b_em, Wc_b, bc_f, flag);

  // ---- CSR build (bucketed two-phase) ----
  hipMemsetAsync(cur_e, 0, NEDGE * 4, stream);
  hipMemsetAsync(cur_v, 0, NVERT * 4, stream);
  hipMemsetAsync(scnt, 0, NSUB * 4, stream);
  const int n4 = NNZ_N / 4;
  count_all<<<(n4 + 255) / 256, 256, 0, stream>>>(
      (const int4*)v_idx, (const int4*)e_idx, cur_v, cur_e, scnt, n4);
  {
    int nbe = (NEDGE + 1023) / 1024, nbv = (NVERT + 1023) / 1024, nbs = (NSUB + 1023) / 1024;
    scan_block<<<nbe, 1024, 0, stream>>>(cur_e, off_e, bsum_e, NEDGE);
    scan_block<<<nbv, 1024, 0, stream>>>(cur_v, off_v, bsum_v, NVERT);
    scan_block<<<nbs, 1024, 0, stream>>>(scnt, sbase, bsum_s, NSUB);
    scan_sums<<<1, 1024, 0, stream>>>(bsum_e, nbe);
    scan_sums<<<1, 1024, 0, stream>>>(bsum_v, nbv);
    scan_sums<<<1, 1024, 0, stream>>>(bsum_s, nbs);
    scan_add<<<(NEDGE + 255) / 256, 256, 0, stream>>>(off_e, bsum_e, NEDGE, NNZ_N);
    scan_add<<<(NVERT + 255) / 256, 256, 0, stream>>>(off_v, bsum_v, NVERT, NNZ_N);
    scan_add<<<(NSUB + 255) / 256, 256, 0, stream>>>(sbase, bsum_s, NSUB, 2 * NNZ_N);
  }
  hipMemcpyAsync(cur_e, off_e, NEDGE * 4, hipMemcpyDeviceToDevice, stream);
  hipMemcpyAsync(cur_v, off_v, NVERT * 4, hipMemcpyDeviceToDevice, stream);
  hipMemcpyAsync(scur, sbase, NSUB * 4, hipMemcpyDeviceToDevice, stream);
  part_pairs<<<(n4 + 255) / 256, 256, 0, stream>>>(
      (const int4*)v_idx, (const int4*)e_idx, scur, pair, n4);
  scatter_adj<<<NBKT, 256, 0, stream>>>(pair, sbase, cur_e, cur_v, adj_e, adj_v);

  // ---- network ----
  // Xp(bf16) = X @ W_tv^T + b_tv
  gemm_mfma<4, false, false, true><<<(NVERT + 63) / 64, 256, 0, stream>>>(
      X, nullptr, Wtv_b, btv_f, Xp_b, nullptr, nullptr, nullptr, NVERT, flag);
  // msg_e(f32) = seg_mean(Xp[v] by e)
  seg_mean_q<<<(NEDGE + 15) / 16, 256, 0, stream>>>(off_e, adj_e, Xp_b, msg_e, NEDGE, NVERT);
  // Ym(bf16) = concat(Y, msg_e) @ Wc^T + bc ; Yo = relu(LN(Ym)) [in-place]
  gemm_mfma<8, true, true, true><<<(NEDGE + 63) / 64, 256, 0, stream>>>(
      Y, msg_e, Wc_b, bc_f, Ym_b, Yo, g_e, be_e, NEDGE, flag);
  // msg_v(f32) = seg_mean(Ym[e] by v) [over dead Xp+pair]
  seg_mean_q<<<(NVERT + 15) / 16, 256, 0, stream>>>(off_v, adj_v, Ym_b, msg_v, NVERT, NEDGE);
  // Xo = relu(LN(concat(X, msg_v) @ W_vm^T + b_vm)) [in-place]
  gemm_mfma<8, true, true, false><<<(NVERT + 63) / 64, 256, 0, stream>>>(
      X, msg_v, Wvm_b, bvm_f, nullptr, Xo, g_v, be_v, NVERT, flag);
}